// Round 19
// baseline (127.906 us; speedup 1.0000x reference)
//
#include <hip/hip_runtime.h>

typedef __attribute__((ext_vector_type(8))) short short8;
typedef __attribute__((ext_vector_type(4))) float f32x4;
typedef __attribute__((ext_vector_type(16))) float f32x16;

#define DEV __device__ __forceinline__

constexpr int Bb = 2, Ss = 2048, Tt = 2048, Ee = 1024, Hh = 16, HDd = 64;
constexpr int Mm = Bb * Ss;                  // 4096 tokens
constexpr size_t NX = (size_t)Mm * Ee;       // 4194304 elems (also mask count)
constexpr size_t NW = (size_t)Ee * Ee;       // 1048576 elems

// ---- workspace layout (bytes) ----
constexpr size_t OFF_XQ   = 0;               // [M][E] bf16 (row-major, as input)
constexpr size_t OFF_XK   = OFF_XQ + NX * 2;
constexpr size_t OFF_XV   = OFF_XK + NX * 2;
constexpr size_t OFF_WQ   = OFF_XV + NX * 2;
constexpr size_t OFF_WK   = OFF_WQ + NW * 2;
constexpr size_t OFF_WV   = OFF_WK + NW * 2;
constexpr size_t OFF_WO   = OFF_WV + NW * 2;
constexpr size_t OFF_QH   = OFF_WO + NW * 2;   // [B*H][S][64] bf16 (pre-scaled by 0.125*log2e)
constexpr size_t OFF_KH   = OFF_QH + NX * 2;   // [B*H][T][64] bf16
constexpr size_t OFF_VH   = OFF_KH + NX * 2;   // V^T: [B*H][64][T] bf16
constexpr size_t OFF_OB   = OFF_VH + NX * 2;   // [B][S][E] bf16 attention out
constexpr size_t OFF_FLAG = OFF_OB + NX * 2;   // int: 1 if mask has a zero

DEV unsigned short f2bf(float f) {
  union { float f; unsigned u; } v; v.f = f;
  unsigned r = v.u + 0x7fffu + ((v.u >> 16) & 1u);   // RNE
  return (unsigned short)(r >> 16);
}

#define GLDS16(g, l) __builtin_amdgcn_global_load_lds(                         \
    (const __attribute__((address_space(1))) void*)(g),                        \
    (__attribute__((address_space(3))) void*)(l), 16, 0, 0)

// swap hi-half of a with lo-half of b. ONLY safe when a,b are distinct live
// SSA values (identical copies get register-coalesced -> self-swap bug!).
#define PLSWAP(a, b) asm("v_permlane32_swap_b32 %0, %1" : "+v"(a), "+v"(b))
#define CVTPK(d, lo, hi_) asm("v_cvt_pk_bf16_f32 %0, %1, %2" : "=v"(d) : "v"(lo), "v"(hi_))

#if __has_builtin(__builtin_amdgcn_exp2f)
#define EXP2(x) __builtin_amdgcn_exp2f(x)
#else
#define EXP2(x) __expf((x) * 0.69314718f)   // guaranteed native v_exp_f32 path
#endif

constexpr float SCLQ = 0.18033688f;   // 0.125 * log2(e), folded into Q at projection

// ============ prep: X + W f32 -> bf16 converts + mask scan ============
__global__ __launch_bounds__(256) void prep_kernel(
    const float* __restrict__ q, const float* __restrict__ k, const float* __restrict__ v,
    const float* __restrict__ wq, const float* __restrict__ wk,
    const float* __restrict__ wv, const float* __restrict__ wo,
    const int* __restrict__ mask,
    unsigned short* __restrict__ Xq, unsigned short* __restrict__ Xk, unsigned short* __restrict__ Xv,
    unsigned short* __restrict__ Wqb, unsigned short* __restrict__ Wkb,
    unsigned short* __restrict__ Wvb, unsigned short* __restrict__ Wob,
    int* __restrict__ flagZero)
{
  constexpr size_t NXv = NX / 4, NWv = NW / 4;
  constexpr size_t tot = 4 * NXv + 4 * NWv;   // 3 X-segs + 4 W-segs + mask seg
  for (size_t u = (size_t)blockIdx.x * blockDim.x + threadIdx.x; u < tot;
       u += (size_t)gridDim.x * blockDim.x) {
    if (u < 3 * NXv) {
      const float* src; unsigned short* dst; size_t off;
      if (u < NXv)            { src = q; dst = Xq; off = u; }
      else if (u < 2 * NXv)   { src = k; dst = Xk; off = u - NXv; }
      else                    { src = v; dst = Xv; off = u - 2 * NXv; }
      float4 f = ((const float4*)src)[off];
      ushort4 o; o.x = f2bf(f.x); o.y = f2bf(f.y); o.z = f2bf(f.z); o.w = f2bf(f.w);
      ((ushort4*)dst)[off] = o;
    } else if (u < 3 * NXv + 4 * NWv) {
      size_t uu = u - 3 * NXv;
      int wsel = (int)(uu / NWv); size_t off = uu % NWv;
      const float* src = wsel == 0 ? wq : wsel == 1 ? wk : wsel == 2 ? wv : wo;
      unsigned short* dst = wsel == 0 ? Wqb : wsel == 1 ? Wkb : wsel == 2 ? Wvb : Wob;
      float4 f = ((const float4*)src)[off];
      ushort4 o; o.x = f2bf(f.x); o.y = f2bf(f.y); o.z = f2bf(f.z); o.w = f2bf(f.w);
      ((ushort4*)dst)[off] = o;
    } else {
      size_t off = u - 3 * NXv - 4 * NWv;
      int4 m = ((const int4*)mask)[off];
      if (m.x == 0 || m.y == 0 || m.z == 0 || m.w == 0) *flagZero = 1;
    }
  }
}

// ============ 128x128 GEMM core, 512 threads / 8 waves, double-buffer (bf16 A+B) ============
DEV void gemm128_8w(const unsigned short* __restrict__ A, const unsigned short* __restrict__ Bm,
                    unsigned short (*Asm)[128 * 32], unsigned short (*Bsm)[128 * 32],
                    f32x4 acc[2][4], int K)
{
  const int tid = threadIdx.x, w = tid >> 6, lane = tid & 63;
  const int l15 = lane & 15, l4 = lane >> 4;
  const int wm = w >> 1, wn = w & 1;
  const int grow = tid >> 2, gk = (tid & 3) * 8;
#pragma unroll
  for (int mi = 0; mi < 2; ++mi)
#pragma unroll
    for (int ni = 0; ni < 4; ++ni) acc[mi][ni] = (f32x4){0.f, 0.f, 0.f, 0.f};

#define GSTAGE8(d, k0)                                                   \
  {                                                                      \
    GLDS16(A  + (size_t)grow * K + (k0) + gk, Asm[d] + w * 512);         \
    GLDS16(Bm + (size_t)grow * K + (k0) + gk, Bsm[d] + w * 512);         \
  }

  GSTAGE8(0, 0)
  int it = 0;
  for (int k0 = 0; k0 < K; k0 += 32, ++it) {
    const int cur = it & 1;
    asm volatile("s_waitcnt vmcnt(0)" ::: "memory");
    __builtin_amdgcn_s_barrier();
    if (k0 + 32 < K) GSTAGE8(cur ^ 1, k0 + 32)

    short8 af[2], bf[4];
#pragma unroll
    for (int mi = 0; mi < 2; ++mi)
      af[mi] = *(const short8*)&Asm[cur][(wm * 32 + mi * 16 + l15) * 32 + l4 * 8];
#pragma unroll
    for (int ni = 0; ni < 4; ++ni)
      bf[ni] = *(const short8*)&Bsm[cur][(wn * 64 + ni * 16 + l15) * 32 + l4 * 8];
    __builtin_amdgcn_s_setprio(1);
#pragma unroll
    for (int mi = 0; mi < 2; ++mi)
#pragma unroll
      for (int ni = 0; ni < 4; ++ni)
        acc[mi][ni] = __builtin_amdgcn_mfma_f32_16x16x32_bf16(af[mi], bf[ni], acc[mi][ni], 0, 0, 0);
    __builtin_amdgcn_s_setprio(0);
  }
#undef GSTAGE8
}

// ============ QKV projection (512 thr, bf16 A; XCD swizzle; V transposed; Q pre-scaled) ============
__global__ __launch_bounds__(512) void gemm_qkv(
    const unsigned short* __restrict__ Xq, const unsigned short* __restrict__ Xk,
    const unsigned short* __restrict__ Xv,
    const unsigned short* __restrict__ Wqb, const unsigned short* __restrict__ Wkb,
    const unsigned short* __restrict__ Wvb,
    const float* __restrict__ bq, const float* __restrict__ bk, const float* __restrict__ bv,
    unsigned short* __restrict__ Qh, unsigned short* __restrict__ Kh, unsigned short* __restrict__ Vh)
{
  __shared__ unsigned short Asm[2][128 * 32], Bsm[2][128 * 32];   // 32 KB
  // T1 XCD swizzle: 768 blocks, 768%8==0 -> bijective chunked remap.
  // Each XCD: 12 bf16 A-panels (3 MB, L2-resident, 8x reuse) + 8 B-panels (2 MB).
  const int orig = (blockIdx.z * 32 + blockIdx.y) * 8 + blockIdx.x;
  const int sid  = (orig & 7) * 96 + (orig >> 3);
  const int z  = sid >> 8;
  const int by = (sid & 255) >> 3, bx = sid & 7;
  const unsigned short* A  = (z == 0) ? Xq  : (z == 1) ? Xk  : Xv;
  const unsigned short* Bw = (z == 0) ? Wqb : (z == 1) ? Wkb : Wvb;
  const float* bias        = (z == 0) ? bq  : (z == 1) ? bk  : bv;
  unsigned short* Out      = (z == 0) ? Qh  : (z == 1) ? Kh  : Vh;
  f32x4 acc[2][4];
  gemm128_8w(A + (size_t)by * 128 * Ee, Bw + (size_t)bx * 128 * Ee, Asm, Bsm, acc, Ee);
  const int tid = threadIdx.x, w = tid >> 6, lane = tid & 63;
  const int l15 = lane & 15, l4 = lane >> 4;
  const int wm = w >> 1, wn = w & 1;
  if (z < 2) {
    const float osc = (z == 0) ? SCLQ : 1.0f;
#pragma unroll
    for (int ni = 0; ni < 4; ++ni) {
      int col = bx * 128 + wn * 64 + ni * 16 + l15;
      float bcol = bias[col];
      int h = col >> 6, hd = col & 63;
#pragma unroll
      for (int mi = 0; mi < 2; ++mi) {
#pragma unroll
        for (int r = 0; r < 4; ++r) {
          int row = by * 128 + wm * 32 + mi * 16 + l4 * 4 + r;
          int b = row >> 11, s = row & 2047;
          Out[(((size_t)(b * Hh + h)) * Ss + s) * HDd + hd] = f2bf((acc[mi][ni][r] + bcol) * osc);
        }
      }
    }
  } else {
    // V^T: Out[((b*H + h)*64 + hd)*S + s], 4 consecutive s per thread -> ushort4
#pragma unroll
    for (int ni = 0; ni < 4; ++ni) {
      int col = bx * 128 + wn * 64 + ni * 16 + l15;
      float bcol = bias[col];
      int h = col >> 6, hd = col & 63;
#pragma unroll
      for (int mi = 0; mi < 2; ++mi) {
        int row = by * 128 + wm * 32 + mi * 16 + l4 * 4;
        int b = row >> 11, s = row & 2047;
        ushort4 pk;
        pk.x = f2bf(acc[mi][ni][0] + bcol); pk.y = f2bf(acc[mi][ni][1] + bcol);
        pk.z = f2bf(acc[mi][ni][2] + bcol); pk.w = f2bf(acc[mi][ni][3] + bcol);
        *(ushort4*)&Out[((size_t)((b * Hh + h) * HDd + hd)) * Ss + s] = pk;
      }
    }
  }
}

// ============ output projection: 512 threads, 8 waves, XCD-chunked swizzle ============
__global__ __launch_bounds__(512) void gemm_out(
    const unsigned short* __restrict__ Ob, const unsigned short* __restrict__ Wob,
    const float* __restrict__ bo, float* __restrict__ out)
{
  __shared__ unsigned short Asm[2][128 * 32], Bsm[2][128 * 32];
  // T1 XCD swizzle: 256 blocks, 256%8==0 -> each XCD gets 32 consecutive ids.
  const int orig = blockIdx.y * 8 + blockIdx.x;
  const int sid  = (orig & 7) * 32 + (orig >> 3);
  const int by = sid >> 3, bx = sid & 7;
  f32x4 acc[2][4];
  gemm128_8w(Ob + (size_t)by * 128 * Ee, Wob + (size_t)bx * 128 * Ee, Asm, Bsm, acc, Ee);
  const int tid = threadIdx.x, w = tid >> 6, lane = tid & 63;
  const int l15 = lane & 15, l4 = lane >> 4;
  const int wm = w >> 1, wn = w & 1;
#pragma unroll
  for (int ni = 0; ni < 4; ++ni) {
    int col = bx * 128 + wn * 64 + ni * 16 + l15;
    float bcol = bo[col];
#pragma unroll
    for (int mi = 0; mi < 2; ++mi) {
#pragma unroll
      for (int r = 0; r < 4; ++r) {
        int row = by * 128 + wm * 32 + mi * 16 + l4 * 4 + r;
        out[(size_t)row * Ee + col] = acc[mi][ni][r] + bcol;
      }
    }
  }
}

// ============ flash attention v11: merged-phase PV(t) ∥ QK(t+1), XCD-bh clustering ============
__global__ __launch_bounds__(256, 4) void attn_kernel(
    const unsigned short* __restrict__ Qh, const unsigned short* __restrict__ Kh,
    const unsigned short* __restrict__ Vh, const int* __restrict__ mask,
    const int* __restrict__ flagZero, unsigned short* __restrict__ Ob)
{
  __shared__ unsigned short Ks[2][64 * 64];   // [dbuf][t][d], 16B-chunk ^= (t&7)
  __shared__ unsigned short Vs[2][64 * 64];   // [dbuf][hd][t], 16B-chunk ^= (hd&7)
  // XCD-bh clustering: each XCD owns 4 heads -> K/V (2MB) L2-resident.
  const int orig = blockIdx.y * 32 + blockIdx.x;
  const int slot = orig >> 3;
  const int bh = (orig & 7) * 4 + (slot >> 5);
  const int qt = slot & 31;
  const int tid = threadIdx.x, w = tid >> 6, lane = tid & 63;
  const int l31 = lane & 31, hi = lane >> 5;
  const int g = w >> 1, p = w & 1;
  const bool useMask = (*flagZero != 0);
  const size_t bhBase = (size_t)bh * Ss * HDd;   // same constant for Kh and V^T
  const int s0 = qt * 64 + g * 32;
  const int trow = p * 32 + l31;

  // Q fragments (B-operand): Q[s0 + l31][ks*16 + hi*8 + j]  (Q already carries SCLQ)
  short8 qf[4];
#pragma unroll
  for (int ks = 0; ks < 4; ++ks)
    qf[ks] = *(const short8*)&Qh[bhBase + (size_t)(s0 + l31) * 64 + ks * 16 + hi * 8];

  f32x16 o0, o1, Z16;
#pragma unroll
  for (int r = 0; r < 16; ++r) { o0[r] = 0.f; o1[r] = 0.f; Z16[r] = 0.f; }
  float l_r = 0.f;

  // staging chunk map: 512 chunks per 64x64 tile; row = i*32 + tid>>3, slot = tid&7
  const int cRow = tid >> 3, cG = (tid & 7) ^ (cRow & 7);

  // K loads issue FIRST (top-of-iter vmcnt(2) = V(t) + K(t+1) landed)
#define STAGE(d, kt2)                                                                         \
  {                                                                                           \
    _Pragma("unroll")                                                                         \
    for (int i = 0; i < 2; ++i)                                                               \
      GLDS16(Kh + bhBase + (size_t)((kt2) + i * 32 + cRow) * 64 + cG * 8,                     \
             &Ks[d][0] + (i * 256 + w * 64) * 8);                                             \
    _Pragma("unroll")                                                                         \
    for (int i = 0; i < 2; ++i)                                                               \
      GLDS16(Vh + bhBase + (size_t)(i * 32 + cRow) * Ss + (kt2) + cG * 8,                     \
             &Vs[d][0] + (i * 256 + w * 64) * 8);                                             \
  }

  // softmax(t+1): mask, exp2, l-accumulate, pack pr -> pa
#define SMPACK(kt2)                                                                           \
  {                                                                                           \
    if (useMask) {                                                                            \
      int sg = s0 + l31;                                                                      \
      _Pragma("unroll")                                                                       \
      for (int r = 0; r < 16; ++r) {                                                          \
        int tg = (kt2) + p * 32 + (r & 3) + 8 * (r >> 2) + 4 * hi;                            \
        if (mask[(size_t)sg * Tt + tg] == 0) pr[r] = -1e30f;                                  \
      }                                                                                       \
    }                                                                                         \
    _Pragma("unroll")                                                                         \
    for (int r = 0; r < 16; ++r) pr[r] = EXP2(pr[r]);                                         \
    float a0 = (pr[0] + pr[1]) + (pr[2] + pr[3]);                                             \
    float a1 = (pr[4] + pr[5]) + (pr[6] + pr[7]);                                             \
    float a2 = (pr[8] + pr[9]) + (pr[10] + pr[11]);                                           \
    float a3 = (pr[12] + pr[13]) + (pr[14] + pr[15]);                                         \
    l_r += (a0 + a1) + (a2 + a3);                                                             \
    _Pragma("unroll")                                                                         \
    for (int h2 = 0; h2 < 2; ++h2) {                                                          \
      unsigned c0, c1, d0, d1; const int bse = h2 * 8;                                        \
      CVTPK(c0, pr[bse + 0], pr[bse + 1]);                                                    \
      CVTPK(c1, pr[bse + 2], pr[bse + 3]);                                                    \
      CVTPK(d0, pr[bse + 4], pr[bse + 5]);                                                    \
      CVTPK(d1, pr[bse + 6], pr[bse + 7]);                                                    \
      PLSWAP(c0, d0); PLSWAP(c1, d1);                                                         \
      union { unsigned u[4]; short8 s; } cc;                                                  \
      cc.u[0] = c0; cc.u[1] = c1; cc.u[2] = d0; cc.u[3] = d1;                                 \
      pa[h2] = cc.s;                                                                          \
    }                                                                                         \
  }

  f32x16 pr;
  short8 pa[2];

  // ---- prologue: stage(0), QK(0), sm(0), pack(0) ----
  STAGE(0, 0)
  asm volatile("s_waitcnt vmcnt(2)" ::: "memory");   // K(0) landed
  __builtin_amdgcn_s_barrier();
  STAGE(1, 64)
  {
    const unsigned short* Kc = &Ks[0][0];
    short8 ka = *(const short8*)&Kc[trow * 64 + ((hi ^ (l31 & 7)) * 8)];
    pr = __builtin_amdgcn_mfma_f32_32x32x16_bf16(ka, qf[0], Z16, 0, 0, 0);
#pragma unroll
    for (int ks = 1; ks < 4; ++ks) {
      short8 kb = *(const short8*)&Kc[trow * 64 + (((ks * 2 + hi) ^ (l31 & 7)) * 8)];
      pr = __builtin_amdgcn_mfma_f32_32x32x16_bf16(kb, qf[ks], pr, 0, 0, 0);
    }
  }
  SMPACK(0)

  for (int t = 0; t < 32; ++t) {
    const int cur = t & 1;
    if (t < 31) { asm volatile("s_waitcnt vmcnt(2)" ::: "memory"); }   // V(t)+K(t+1) in
    else        { asm volatile("s_waitcnt vmcnt(0)" ::: "memory"); }
    __builtin_amdgcn_s_barrier();   // buffers ready; prior readers of buf[cur^1] done

    const unsigned short* Vc = &Vs[cur][0];
    __builtin_amdgcn_s_setprio(1);
    if (t < 31) {
      // merged MFMA phase: PV(t) [Vs[cur]] ∥ QK(t+1) [Ks[cur^1]] — 3 indep chains
      const unsigned short* Kn = &Ks[cur ^ 1][0];
      short8 ka0 = *(const short8*)&Kn[trow * 64 + (((0 + hi) ^ (l31 & 7)) * 8)];
      short8 ka1 = *(const short8*)&Kn[trow * 64 + (((2 + hi) ^ (l31 & 7)) * 8)];
      short8 ka2 = *(const short8*)&Kn[trow * 64 + (((4 + hi) ^ (l31 & 7)) * 8)];
      short8 ka3 = *(const short8*)&Kn[trow * 64 + (((6 + hi) ^ (l31 & 7)) * 8)];
      short8 vf00 = *(const short8*)&Vc[l31 * 64 + (((p * 4 + 0 + hi) ^ (l31 & 7)) * 8)];
      short8 vf01 = *(const short8*)&Vc[(32 + l31) * 64 + (((p * 4 + 0 + hi) ^ ((l31 & 7))) * 8)];
      short8 vf10 = *(const short8*)&Vc[l31 * 64 + (((p * 4 + 2 + hi) ^ (l31 & 7)) * 8)];
      short8 vf11 = *(const short8*)&Vc[(32 + l31) * 64 + (((p * 4 + 2 + hi) ^ ((l31 & 7))) * 8)];
      f32x16 prN;
      prN = __builtin_amdgcn_mfma_f32_32x32x16_bf16(ka0, qf[0], Z16, 0, 0, 0);
      o0  = __builtin_amdgcn_mfma_f32_32x32x16_bf16(pa[0], vf00, o0, 0, 0, 0);
      o1  = __builtin_amdgcn_mfma_f32_32x32x16_bf16(pa[0], vf01, o1, 0, 0, 0);
      prN = __builtin_amdgcn_mfma_f32_32x32x16_bf16(ka1, qf[1], prN, 0, 0, 0);
      o0  = __builtin_amdgcn_mfma_f32_32x32x16_bf16(pa[1], vf10, o0, 0, 0, 0);
      prN = __builtin_amdgcn_mfma_f32_32x32x16_bf16(ka2, qf[2], prN, 0, 0, 0);
      o1  = __builtin_amdgcn_mfma_f32_32x32x16_bf16(pa[1], vf11, o1, 0, 0, 0);
      prN = __builtin_amdgcn_mfma_f32_32x32x16_bf16(ka3, qf[3], prN, 0, 0, 0);
      pr = prN;
    } else {
      // final tile: PV only
      short8 vf00 = *(const short8*)&Vc[l31 * 64 + (((p * 4 + 0 + hi) ^ (l31 & 7)) * 8)];
      short8 vf01 = *(const short8*)&Vc[(32 + l31) * 64 + (((p * 4 + 0 + hi) ^ ((l31 & 7))) * 8)];
      short8 vf10 = *(const short8*)&Vc[l31 * 64 + (((p * 4 + 2 + hi) ^ (l31 & 7)) * 8)];
      short8 vf11 = *(const short8*)&Vc[(32 + l31) * 64 + (((p * 4 + 2 + hi) ^ ((l31 & 7))) * 8)];
      o0 = __builtin_amdgcn_mfma_f32_32x32x16_bf16(pa[0], vf00, o0, 0, 0, 0);
      o1 = __builtin_amdgcn_mfma_f32_32x32x16_bf16(pa[0], vf01, o1, 0, 0, 0);
      o0 = __builtin_amdgcn_mfma_f32_32x32x16_bf16(pa[1], vf10, o0, 0, 0, 0);
      o1 = __builtin_amdgcn_mfma_f32_32x32x16_bf16(pa[1], vf11, o1, 0, 0, 0);
    }
    __builtin_amdgcn_s_setprio(0);

    if (t < 31) SMPACK((t + 1) * 64)

    __builtin_amdgcn_s_barrier();   // buf[cur] fully dead (Ks read at t-1, Vs read now)
    if (t < 30) STAGE(cur, (t + 2) * 64)
  }
#undef STAGE
#undef SMPACK

  __syncthreads();   // all waves done with Ks/Vs before LDS reuse below

  // ---- additive parity merge (no-max softmax => O and l just sum) ----
  float* Ox = (float*)&Ks[0][0];       // [g][32 sr][64 col] f32 = 16 KB
  float* Ml = (float*)&Vs[0][0];       // [g][32] f32
  float lt = l_r + __shfl_xor(l_r, 32);    // own-parity row sum (both hi halves)
  if (p == 1) {
#pragma unroll
    for (int r = 0; r < 16; ++r) {
      int sr = (r & 3) + 8 * (r >> 2) + 4 * hi;
      Ox[g * 2048 + sr * 64 + l31]      = o0[r];
      Ox[g * 2048 + sr * 64 + 32 + l31] = o1[r];
    }
    if (hi == 0) Ml[g * 32 + l31] = lt;
  }
  __syncthreads();
  if (p == 0) {
    const int b = bh >> 4, h = bh & 15;
    float ltot = lt + Ml[g * 32 + l31];
    float linv = ltot > 0.f ? 1.0f / ltot : 0.f;
#pragma unroll
    for (int r = 0; r < 16; ++r) {
      int sr = (r & 3) + 8 * (r >> 2) + 4 * hi;
      float li = __shfl(linv, sr);
      size_t rowbase = (size_t)(b * Ss + s0 + sr) * Ee + h * 64;
      Ob[rowbase + l31]      = f2bf((o0[r] + Ox[g * 2048 + sr * 64 + l31]) * li);
      Ob[rowbase + 32 + l31] = f2bf((o1[r] + Ox[g * 2048 + sr * 64 + 32 + l31]) * li);
    }
  }
}

extern "C" void kernel_launch(void* const* d_in, const int* in_sizes, int n_in,
                              void* d_out, int out_size, void* d_ws, size_t ws_size,
                              hipStream_t stream) {
  const float* q   = (const float*)d_in[0];
  const float* k   = (const float*)d_in[1];
  const float* v   = (const float*)d_in[2];
  const int*  msk  = (const int*)d_in[3];
  const float* Wq  = (const float*)d_in[4];
  const float* bq  = (const float*)d_in[5];
  const float* Wk  = (const float*)d_in[6];
  const float* bk  = (const float*)d_in[7];
  const float* Wv  = (const float*)d_in[8];
  const float* bv  = (const float*)d_in[9];
  const float* Wo  = (const float*)d_in[10];
  const float* bo  = (const float*)d_in[11];
  float* out = (float*)d_out;

  char* ws = (char*)d_ws;
  unsigned short* Xq  = (unsigned short*)(ws + OFF_XQ);
  unsigned short* Xk  = (unsigned short*)(ws + OFF_XK);
  unsigned short* Xv  = (unsigned short*)(ws + OFF_XV);
  unsigned short* Wqb = (unsigned short*)(ws + OFF_WQ);
  unsigned short* Wkb = (unsigned short*)(ws + OFF_WK);
  unsigned short* Wvb = (unsigned short*)(ws + OFF_WV);
  unsigned short* Wob = (unsigned short*)(ws + OFF_WO);
  unsigned short* Qh  = (unsigned short*)(ws + OFF_QH);
  unsigned short* Kh  = (unsigned short*)(ws + OFF_KH);
  unsigned short* Vh  = (unsigned short*)(ws + OFF_VH);
  unsigned short* Ob  = (unsigned short*)(ws + OFF_OB);
  int* flagZero       = (int*)(ws + OFF_FLAG);

  hipMemsetAsync(flagZero, 0, 4, stream);
  prep_kernel<<<4096, 256, 0, stream>>>(q, k, v, Wq, Wk, Wv, Wo, msk,
                                        Xq, Xk, Xv, Wqb, Wkb, Wvb, Wob, flagZero);
  gemm_qkv<<<dim3(8, 32, 3), 512, 0, stream>>>(Xq, Xk, Xv, Wqb, Wkb, Wvb,
                                               bq, bk, bv, Qh, Kh, Vh);
  attn_kernel<<<dim3(32, 32), 256, 0, stream>>>(Qh, Kh, Vh, msk, flagZero, Ob);
  gemm_out<<<dim3(8, 32), 512, 0, stream>>>(Ob, Wob, bo, out);
}

// Round 20
// 121.671 us; speedup vs baseline: 1.0512x; 1.0512x over previous
//
#include <hip/hip_runtime.h>

typedef __attribute__((ext_vector_type(8))) short short8;
typedef __attribute__((ext_vector_type(4))) float f32x4;
typedef __attribute__((ext_vector_type(16))) float f32x16;

#define DEV __device__ __forceinline__

constexpr int Bb = 2, Ss = 2048, Tt = 2048, Ee = 1024, Hh = 16, HDd = 64;
constexpr int Mm = Bb * Ss;                  // 4096 tokens
constexpr size_t NX = (size_t)Mm * Ee;       // 4194304 elems (also mask count)
constexpr size_t NW = (size_t)Ee * Ee;       // 1048576 elems

// ---- workspace layout (bytes) ----
constexpr size_t OFF_WQ   = 0;
constexpr size_t OFF_WK   = OFF_WQ + NW * 2;
constexpr size_t OFF_WV   = OFF_WK + NW * 2;
constexpr size_t OFF_WO   = OFF_WV + NW * 2;
constexpr size_t OFF_QH   = OFF_WO + NW * 2;   // [B*H][S][64] bf16 (pre-scaled by 0.125*log2e)
constexpr size_t OFF_KH   = OFF_QH + NX * 2;   // [B*H][T][64] bf16
constexpr size_t OFF_VH   = OFF_KH + NX * 2;   // V^T: [B*H][64][T] bf16
constexpr size_t OFF_OB   = OFF_VH + NX * 2;   // [B][S][E] bf16 attention out
constexpr size_t OFF_FLAG = OFF_OB + NX * 2;   // int: 1 if mask has a zero

DEV unsigned short f2bf(float f) {
  union { float f; unsigned u; } v; v.f = f;
  unsigned r = v.u + 0x7fffu + ((v.u >> 16) & 1u);   // RNE
  return (unsigned short)(r >> 16);
}

#define GLDS16(g, l) __builtin_amdgcn_global_load_lds(                         \
    (const __attribute__((address_space(1))) void*)(g),                        \
    (__attribute__((address_space(3))) void*)(l), 16, 0, 0)

// swap hi-half of a with lo-half of b. ONLY safe when a,b are distinct live
// SSA values (identical copies get register-coalesced -> self-swap bug!).
#define PLSWAP(a, b) asm("v_permlane32_swap_b32 %0, %1" : "+v"(a), "+v"(b))
#define CVTPK(d, lo, hi_) asm("v_cvt_pk_bf16_f32 %0, %1, %2" : "=v"(d) : "v"(lo), "v"(hi_))

#if __has_builtin(__builtin_amdgcn_exp2f)
#define EXP2(x) __builtin_amdgcn_exp2f(x)
#else
#define EXP2(x) __expf((x) * 0.69314718f)   // guaranteed native v_exp_f32 path
#endif

constexpr float SCLQ = 0.18033688f;   // 0.125 * log2(e), folded into Q at projection

// ============ prep v2: W f32 -> bf16 + mask scan (X handled in gemm_qkv) ============
__global__ __launch_bounds__(256) void prep_kernel(
    const float* __restrict__ wq, const float* __restrict__ wk,
    const float* __restrict__ wv, const float* __restrict__ wo,
    const int* __restrict__ mask,
    unsigned short* __restrict__ Wqb, unsigned short* __restrict__ Wkb,
    unsigned short* __restrict__ Wvb, unsigned short* __restrict__ Wob,
    int* __restrict__ flagZero)
{
  constexpr size_t NWv = NW / 4, NXv = NX / 4;
  constexpr size_t tot = 4 * NWv + NXv;
  for (size_t u = (size_t)blockIdx.x * blockDim.x + threadIdx.x; u < tot;
       u += (size_t)gridDim.x * blockDim.x) {
    if (u < 4 * NWv) {
      int wsel = (int)(u / NWv); size_t off = u % NWv;
      const float* src = wsel == 0 ? wq : wsel == 1 ? wk : wsel == 2 ? wv : wo;
      unsigned short* dst = wsel == 0 ? Wqb : wsel == 1 ? Wkb : wsel == 2 ? Wvb : Wob;
      float4 f = ((const float4*)src)[off];
      ushort4 o; o.x = f2bf(f.x); o.y = f2bf(f.y); o.z = f2bf(f.z); o.w = f2bf(f.w);
      ((ushort4*)dst)[off] = o;
    } else {
      size_t off = u - 4 * NWv;
      int4 m = ((const int4*)mask)[off];
      if (m.x == 0 || m.y == 0 || m.z == 0 || m.w == 0) *flagZero = 1;
    }
  }
}

// ============ 128x128 GEMM core, A from f32: counted pipeline, 2-iter A AND B lead ============
// Asm double-buffered (reg sets X/Y), Bsm TRIPLE-buffered (B(j) lives in Bsm[j%3]).
// Steady iter t: issue B(t+2)+A(t+2) -> compute(t) -> vmcnt(6) [A(t+1),B(t+1) landed;
// A(t+2)4+B(t+2)2 in flight] -> cvt+ds_write A(t+1) -> lgkmcnt(0) -> raw s_barrier.
DEV void gemm128_f32A(const float* __restrict__ Af, const unsigned short* __restrict__ Bm,
                      unsigned short (*Asm)[128 * 32], unsigned short (*Bsm)[128 * 32],
                      f32x4 acc[4][4], int K)
{
  const int t = threadIdx.x;
  const int w = t >> 6, lane = t & 63;
  const int l15 = lane & 15, l4 = lane >> 4;
  const int wm = w >> 1, wn = w & 1;
  const int srow = lane >> 2;          // B staging row within 16-row slab
  const int skc  = (lane & 3) * 8;
  const int ar = t >> 2;               // A row 0..63 (and +64)
  const int ak = (t & 3) * 8;          // A k-octet
#pragma unroll
  for (int mi = 0; mi < 4; ++mi)
#pragma unroll
    for (int ni = 0; ni < 4; ++ni) acc[mi][ni] = (f32x4){0.f, 0.f, 0.f, 0.f};

  float4 x0, x1, x2, x3;   // set X (even tiles)
  float4 y0, y1, y2, y3;   // set Y (odd tiles)

#define ALOAD(r0, r1, r2, r3, k0)                                            \
  { const float* ap  = Af + (size_t)ar * K + (k0) + ak;                      \
    const float* ap2 = ap + (size_t)64 * K;                                  \
    r0 = *(const float4*)ap;  r1 = *(const float4*)(ap + 4);                 \
    r2 = *(const float4*)ap2; r3 = *(const float4*)(ap2 + 4); }
#define BSTAGE(d, k0)                                                        \
  { GLDS16(Bm + (size_t)(w * 16 + srow) * K + (k0) + skc,      Bsm[d] + w * 512);        \
    GLDS16(Bm + (size_t)(64 + w * 16 + srow) * K + (k0) + skc, Bsm[d] + 2048 + w * 512); }
#define AWRITE(d, r0, r1, r2, r3)                                            \
  { unsigned u0, u1, u2, u3, u4, u5, u6, u7;                                 \
    CVTPK(u0, r0.x, r0.y); CVTPK(u1, r0.z, r0.w);                            \
    CVTPK(u2, r1.x, r1.y); CVTPK(u3, r1.z, r1.w);                            \
    CVTPK(u4, r2.x, r2.y); CVTPK(u5, r2.z, r2.w);                            \
    CVTPK(u6, r3.x, r3.y); CVTPK(u7, r3.z, r3.w);                            \
    union { unsigned u[4]; short8 s; } p0, p1;                               \
    p0.u[0] = u0; p0.u[1] = u1; p0.u[2] = u2; p0.u[3] = u3;                  \
    p1.u[0] = u4; p1.u[1] = u5; p1.u[2] = u6; p1.u[3] = u7;                  \
    *(short8*)&Asm[d][ar * 32 + ak]        = p0.s;                           \
    *(short8*)&Asm[d][(64 + ar) * 32 + ak] = p1.s; }
#define COMP(abuf, bbuf)                                                     \
  { short8 af[4], bf[4];                                                     \
    _Pragma("unroll")                                                        \
    for (int mi = 0; mi < 4; ++mi)                                           \
      af[mi] = *(const short8*)&Asm[abuf][(wm * 64 + mi * 16 + l15) * 32 + l4 * 8]; \
    _Pragma("unroll")                                                        \
    for (int ni = 0; ni < 4; ++ni)                                           \
      bf[ni] = *(const short8*)&Bsm[bbuf][(wn * 64 + ni * 16 + l15) * 32 + l4 * 8]; \
    __builtin_amdgcn_s_setprio(1);                                           \
    _Pragma("unroll")                                                        \
    for (int mi = 0; mi < 4; ++mi)                                           \
      _Pragma("unroll")                                                      \
      for (int ni = 0; ni < 4; ++ni)                                         \
        acc[mi][ni] = __builtin_amdgcn_mfma_f32_16x16x32_bf16(af[mi], bf[ni], acc[mi][ni], 0, 0, 0); \
    __builtin_amdgcn_s_setprio(0); }

  // ---- prologue ----
  ALOAD(x0, x1, x2, x3, 0)
  BSTAGE(0, 0)                                       // out: X4 + B0(2) = 6
  asm volatile("s_waitcnt vmcnt(2)" ::: "memory");   // X(tile0) landed
  AWRITE(0, x0, x1, x2, x3)
  ALOAD(y0, y1, y2, y3, 32)                          // out: B0(2) + Y4 = 6
  BSTAGE(1, 32)                                      // out: 8
  asm volatile("s_waitcnt vmcnt(6)" ::: "memory");   // B0 landed; Y4+B1(2) in flight
  asm volatile("s_waitcnt lgkmcnt(0)" ::: "memory");
  __builtin_amdgcn_s_barrier();

  // nt = 32 tiles (K=1024). Main loop covers t=0..29 (15 even/odd pairs).
  for (int tt = 0; tt < 30; tt += 2) {
    const int be = tt % 3, bo = (tt + 1) % 3, bn = (tt + 2) % 3, bn2 = (tt + 3) % 3;
    // t = tt (even): A Asm[0], B Bsm[be]; entering in-flight = Y(t+1)4 + B(t+1)2
    BSTAGE(bn, (tt + 2) * 32)
    ALOAD(x0, x1, x2, x3, (tt + 2) * 32)
    COMP(0, be)
    asm volatile("s_waitcnt vmcnt(6)" ::: "memory"); // Y(t+1)+B(t+1) landed
    AWRITE(1, y0, y1, y2, y3)
    asm volatile("s_waitcnt lgkmcnt(0)" ::: "memory");
    __builtin_amdgcn_s_barrier();
    // t = tt+1 (odd): A Asm[1], B Bsm[bo]; entering in-flight = X(t+1)4 + B(t+1)2
    BSTAGE(bn2, (tt + 3) * 32)
    ALOAD(y0, y1, y2, y3, (tt + 3) * 32)
    COMP(1, bo)
    asm volatile("s_waitcnt vmcnt(6)" ::: "memory"); // X(t+1)+B(t+1) landed
    AWRITE(0, x0, x1, x2, x3)
    asm volatile("s_waitcnt lgkmcnt(0)" ::: "memory");
    __builtin_amdgcn_s_barrier();
  }
  // t = 30 (even): A Asm[0], B Bsm[0]; in-flight = Y(31)4 + B(31)2
  COMP(0, 0)
  asm volatile("s_waitcnt vmcnt(2)" ::: "memory");   // Y(31) landed; B(31) in flight
  AWRITE(1, y0, y1, y2, y3)
  asm volatile("s_waitcnt lgkmcnt(0)" ::: "memory");
  __builtin_amdgcn_s_barrier();
  // t = 31 (odd): A Asm[1], B Bsm[1]
  asm volatile("s_waitcnt vmcnt(0)" ::: "memory");   // B(31) landed
  COMP(1, 1)
#undef ALOAD
#undef BSTAGE
#undef AWRITE
#undef COMP
}

// ============ 128x128 GEMM core, 512 threads / 8 waves, double-buffer (bf16 A) ============
DEV void gemm128_8w(const unsigned short* __restrict__ A, const unsigned short* __restrict__ Bm,
                    unsigned short (*Asm)[128 * 32], unsigned short (*Bsm)[128 * 32],
                    f32x4 acc[2][4], int K)
{
  const int tid = threadIdx.x, w = tid >> 6, lane = tid & 63;
  const int l15 = lane & 15, l4 = lane >> 4;
  const int wm = w >> 1, wn = w & 1;
  const int grow = tid >> 2, gk = (tid & 3) * 8;
#pragma unroll
  for (int mi = 0; mi < 2; ++mi)
#pragma unroll
    for (int ni = 0; ni < 4; ++ni) acc[mi][ni] = (f32x4){0.f, 0.f, 0.f, 0.f};

#define GSTAGE8(d, k0)                                                   \
  {                                                                      \
    GLDS16(A  + (size_t)grow * K + (k0) + gk, Asm[d] + w * 512);         \
    GLDS16(Bm + (size_t)grow * K + (k0) + gk, Bsm[d] + w * 512);         \
  }

  GSTAGE8(0, 0)
  int it = 0;
  for (int k0 = 0; k0 < K; k0 += 32, ++it) {
    const int cur = it & 1;
    asm volatile("s_waitcnt vmcnt(0)" ::: "memory");
    __builtin_amdgcn_s_barrier();
    if (k0 + 32 < K) GSTAGE8(cur ^ 1, k0 + 32)

    short8 af[2], bf[4];
#pragma unroll
    for (int mi = 0; mi < 2; ++mi)
      af[mi] = *(const short8*)&Asm[cur][(wm * 32 + mi * 16 + l15) * 32 + l4 * 8];
#pragma unroll
    for (int ni = 0; ni < 4; ++ni)
      bf[ni] = *(const short8*)&Bsm[cur][(wn * 64 + ni * 16 + l15) * 32 + l4 * 8];
    __builtin_amdgcn_s_setprio(1);
#pragma unroll
    for (int mi = 0; mi < 2; ++mi)
#pragma unroll
      for (int ni = 0; ni < 4; ++ni)
        acc[mi][ni] = __builtin_amdgcn_mfma_f32_16x16x32_bf16(af[mi], bf[ni], acc[mi][ni], 0, 0, 0);
    __builtin_amdgcn_s_setprio(0);
  }
#undef GSTAGE8
}

// ============ QKV projection (A from f32 inputs; XCD swizzle; V transposed; Q pre-scaled) ============
__global__ __launch_bounds__(256, 3) void gemm_qkv(
    const float* __restrict__ q, const float* __restrict__ k, const float* __restrict__ v,
    const unsigned short* __restrict__ Wqb, const unsigned short* __restrict__ Wkb,
    const unsigned short* __restrict__ Wvb,
    const float* __restrict__ bq, const float* __restrict__ bk, const float* __restrict__ bv,
    unsigned short* __restrict__ Qh, unsigned short* __restrict__ Kh, unsigned short* __restrict__ Vh)
{
  __shared__ unsigned short Asm[2][128 * 32], Bsm[3][128 * 32];   // 40 KB
  // T1 XCD swizzle: 768 blocks, 768%8==0 -> bijective chunked remap.
  const int orig = (blockIdx.z * 32 + blockIdx.y) * 8 + blockIdx.x;
  const int sid  = (orig & 7) * 96 + (orig >> 3);
  const int z  = sid >> 8;
  const int by = (sid & 255) >> 3, bx = sid & 7;
  const float* A           = (z == 0) ? q   : (z == 1) ? k   : v;
  const unsigned short* Bw = (z == 0) ? Wqb : (z == 1) ? Wkb : Wvb;
  const float* bias        = (z == 0) ? bq  : (z == 1) ? bk  : bv;
  unsigned short* Out      = (z == 0) ? Qh  : (z == 1) ? Kh  : Vh;
  f32x4 acc[4][4];
  gemm128_f32A(A + (size_t)by * 128 * Ee, Bw + (size_t)bx * 128 * Ee, Asm, Bsm, acc, Ee);
  const int t = threadIdx.x, w = t >> 6, lane = t & 63, l15 = lane & 15, l4 = lane >> 4;
  const int wm = w >> 1, wn = w & 1;
  if (z < 2) {
    const float osc = (z == 0) ? SCLQ : 1.0f;
#pragma unroll
    for (int ni = 0; ni < 4; ++ni) {
      int col = bx * 128 + wn * 64 + ni * 16 + l15;
      float bcol = bias[col];
      int h = col >> 6, hd = col & 63;
#pragma unroll
      for (int mi = 0; mi < 4; ++mi) {
#pragma unroll
        for (int r = 0; r < 4; ++r) {
          int row = by * 128 + wm * 64 + mi * 16 + l4 * 4 + r;
          int b = row >> 11, s = row & 2047;
          Out[(((size_t)(b * Hh + h)) * Ss + s) * HDd + hd] = f2bf((acc[mi][ni][r] + bcol) * osc);
        }
      }
    }
  } else {
    // V^T: Out[((b*H + h)*64 + hd)*S + s], 4 consecutive s per thread -> ushort4
#pragma unroll
    for (int ni = 0; ni < 4; ++ni) {
      int col = bx * 128 + wn * 64 + ni * 16 + l15;
      float bcol = bias[col];
      int h = col >> 6, hd = col & 63;
#pragma unroll
      for (int mi = 0; mi < 4; ++mi) {
        int row = by * 128 + wm * 64 + mi * 16 + l4 * 4;
        int b = row >> 11, s = row & 2047;
        ushort4 pk;
        pk.x = f2bf(acc[mi][ni][0] + bcol); pk.y = f2bf(acc[mi][ni][1] + bcol);
        pk.z = f2bf(acc[mi][ni][2] + bcol); pk.w = f2bf(acc[mi][ni][3] + bcol);
        *(ushort4*)&Out[((size_t)((b * Hh + h) * HDd + hd)) * Ss + s] = pk;
      }
    }
  }
}

// ============ output projection: 512 threads, 8 waves, XCD-chunked swizzle ============
__global__ __launch_bounds__(512) void gemm_out(
    const unsigned short* __restrict__ Ob, const unsigned short* __restrict__ Wob,
    const float* __restrict__ bo, float* __restrict__ out)
{
  __shared__ unsigned short Asm[2][128 * 32], Bsm[2][128 * 32];
  // T1 XCD swizzle: 256 blocks, 256%8==0 -> each XCD gets 32 consecutive ids.
  const int orig = blockIdx.y * 8 + blockIdx.x;
  const int sid  = (orig & 7) * 32 + (orig >> 3);
  const int by = sid >> 3, bx = sid & 7;
  f32x4 acc[2][4];
  gemm128_8w(Ob + (size_t)by * 128 * Ee, Wob + (size_t)bx * 128 * Ee, Asm, Bsm, acc, Ee);
  const int tid = threadIdx.x, w = tid >> 6, lane = tid & 63;
  const int l15 = lane & 15, l4 = lane >> 4;
  const int wm = w >> 1, wn = w & 1;
#pragma unroll
  for (int ni = 0; ni < 4; ++ni) {
    int col = bx * 128 + wn * 64 + ni * 16 + l15;
    float bcol = bo[col];
#pragma unroll
    for (int mi = 0; mi < 2; ++mi) {
#pragma unroll
      for (int r = 0; r < 4; ++r) {
        int row = by * 128 + wm * 32 + mi * 16 + l4 * 4 + r;
        out[(size_t)row * Ee + col] = acc[mi][ni][r] + bcol;
      }
    }
  }
}

// ============ flash attention v11: merged-phase PV(t) ∥ QK(t+1), XCD-bh clustering ============
__global__ __launch_bounds__(256, 4) void attn_kernel(
    const unsigned short* __restrict__ Qh, const unsigned short* __restrict__ Kh,
    const unsigned short* __restrict__ Vh, const int* __restrict__ mask,
    const int* __restrict__ flagZero, unsigned short* __restrict__ Ob)
{
  __shared__ unsigned short Ks[2][64 * 64];   // [dbuf][t][d], 16B-chunk ^= (t&7)
  __shared__ unsigned short Vs[2][64 * 64];   // [dbuf][hd][t], 16B-chunk ^= (hd&7)
  // XCD-bh clustering: each XCD owns 4 heads -> K/V (2MB) L2-resident (R19: FETCH 70->12MB).
  const int orig = blockIdx.y * 32 + blockIdx.x;
  const int slot = orig >> 3;
  const int bh = (orig & 7) * 4 + (slot >> 5);
  const int qt = slot & 31;
  const int tid = threadIdx.x, w = tid >> 6, lane = tid & 63;
  const int l31 = lane & 31, hi = lane >> 5;
  const int g = w >> 1, p = w & 1;
  const bool useMask = (*flagZero != 0);
  const size_t bhBase = (size_t)bh * Ss * HDd;   // same constant for Kh and V^T
  const int s0 = qt * 64 + g * 32;
  const int trow = p * 32 + l31;

  // Q fragments (B-operand): Q[s0 + l31][ks*16 + hi*8 + j]  (Q already carries SCLQ)
  short8 qf[4];
#pragma unroll
  for (int ks = 0; ks < 4; ++ks)
    qf[ks] = *(const short8*)&Qh[bhBase + (size_t)(s0 + l31) * 64 + ks * 16 + hi * 8];

  f32x16 o0, o1, Z16;
#pragma unroll
  for (int r = 0; r < 16; ++r) { o0[r] = 0.f; o1[r] = 0.f; Z16[r] = 0.f; }
  float l_r = 0.f;

  // staging chunk map: 512 chunks per 64x64 tile; row = i*32 + tid>>3, slot = tid&7
  const int cRow = tid >> 3, cG = (tid & 7) ^ (cRow & 7);

  // K loads issue FIRST (top-of-iter vmcnt(2) = V(t) + K(t+1) landed)
#define STAGE(d, kt2)                                                                         \
  {                                                                                           \
    _Pragma("unroll")                                                                         \
    for (int i = 0; i < 2; ++i)                                                               \
      GLDS16(Kh + bhBase + (size_t)((kt2) + i * 32 + cRow) * 64 + cG * 8,                     \
             &Ks[d][0] + (i * 256 + w * 64) * 8);                                             \
    _Pragma("unroll")                                                                         \
    for (int i = 0; i < 2; ++i)                                                               \
      GLDS16(Vh + bhBase + (size_t)(i * 32 + cRow) * Ss + (kt2) + cG * 8,                     \
             &Vs[d][0] + (i * 256 + w * 64) * 8);                                             \
  }

  // softmax(t+1): mask, exp2, l-accumulate, pack pr -> pa
#define SMPACK(kt2)                                                                           \
  {                                                                                           \
    if (useMask) {                                                                            \
      int sg = s0 + l31;                                                                      \
      _Pragma("unroll")                                                                       \
      for (int r = 0; r < 16; ++r) {                                                          \
        int tg = (kt2) + p * 32 + (r & 3) + 8 * (r >> 2) + 4 * hi;                            \
        if (mask[(size_t)sg * Tt + tg] == 0) pr[r] = -1e30f;                                  \
      }                                                                                       \
    }                                                                                         \
    _Pragma("unroll")                                                                         \
    for (int r = 0; r < 16; ++r) pr[r] = EXP2(pr[r]);                                         \
    float a0 = (pr[0] + pr[1]) + (pr[2] + pr[3]);                                             \
    float a1 = (pr[4] + pr[5]) + (pr[6] + pr[7]);                                             \
    float a2 = (pr[8] + pr[9]) + (pr[10] + pr[11]);                                           \
    float a3 = (pr[12] + pr[13]) + (pr[14] + pr[15]);                                         \
    l_r += (a0 + a1) + (a2 + a3);                                                             \
    _Pragma("unroll")                                                                         \
    for (int h2 = 0; h2 < 2; ++h2) {                                                          \
      unsigned c0, c1, d0, d1; const int bse = h2 * 8;                                        \
      CVTPK(c0, pr[bse + 0], pr[bse + 1]);                                                    \
      CVTPK(c1, pr[bse + 2], pr[bse + 3]);                                                    \
      CVTPK(d0, pr[bse + 4], pr[bse + 5]);                                                    \
      CVTPK(d1, pr[bse + 6], pr[bse + 7]);                                                    \
      PLSWAP(c0, d0); PLSWAP(c1, d1);                                                         \
      union { unsigned u[4]; short8 s; } cc;                                                  \
      cc.u[0] = c0; cc.u[1] = c1; cc.u[2] = d0; cc.u[3] = d1;                                 \
      pa[h2] = cc.s;                                                                          \
    }                                                                                         \
  }

  f32x16 pr;
  short8 pa[2];

  // ---- prologue: stage(0), QK(0), sm(0), pack(0) ----
  STAGE(0, 0)
  asm volatile("s_waitcnt vmcnt(2)" ::: "memory");   // K(0) landed
  __builtin_amdgcn_s_barrier();
  STAGE(1, 64)
  {
    const unsigned short* Kc = &Ks[0][0];
    short8 ka = *(const short8*)&Kc[trow * 64 + ((hi ^ (l31 & 7)) * 8)];
    pr = __builtin_amdgcn_mfma_f32_32x32x16_bf16(ka, qf[0], Z16, 0, 0, 0);
#pragma unroll
    for (int ks = 1; ks < 4; ++ks) {
      short8 kb = *(const short8*)&Kc[trow * 64 + (((ks * 2 + hi) ^ (l31 & 7)) * 8)];
      pr = __builtin_amdgcn_mfma_f32_32x32x16_bf16(kb, qf[ks], pr, 0, 0, 0);
    }
  }
  SMPACK(0)

  for (int t = 0; t < 32; ++t) {
    const int cur = t & 1;
    if (t < 31) { asm volatile("s_waitcnt vmcnt(2)" ::: "memory"); }   // V(t)+K(t+1) in
    else        { asm volatile("s_waitcnt vmcnt(0)" ::: "memory"); }
    __builtin_amdgcn_s_barrier();   // buffers ready; prior readers of buf[cur^1] done

    const unsigned short* Vc = &Vs[cur][0];
    __builtin_amdgcn_s_setprio(1);
    if (t < 31) {
      // merged MFMA phase: PV(t) [Vs[cur]] ∥ QK(t+1) [Ks[cur^1]] — 3 indep chains
      const unsigned short* Kn = &Ks[cur ^ 1][0];
      short8 ka0 = *(const short8*)&Kn[trow * 64 + (((0 + hi) ^ (l31 & 7)) * 8)];
      short8 ka1 = *(const short8*)&Kn[trow * 64 + (((2 + hi) ^ (l31 & 7)) * 8)];
      short8 ka2 = *(const short8*)&Kn[trow * 64 + (((4 + hi) ^ (l31 & 7)) * 8)];
      short8 ka3 = *(const short8*)&Kn[trow * 64 + (((6 + hi) ^ (l31 & 7)) * 8)];
      short8 vf00 = *(const short8*)&Vc[l31 * 64 + (((p * 4 + 0 + hi) ^ (l31 & 7)) * 8)];
      short8 vf01 = *(const short8*)&Vc[(32 + l31) * 64 + (((p * 4 + 0 + hi) ^ ((l31 & 7))) * 8)];
      short8 vf10 = *(const short8*)&Vc[l31 * 64 + (((p * 4 + 2 + hi) ^ (l31 & 7)) * 8)];
      short8 vf11 = *(const short8*)&Vc[(32 + l31) * 64 + (((p * 4 + 2 + hi) ^ ((l31 & 7))) * 8)];
      f32x16 prN;
      prN = __builtin_amdgcn_mfma_f32_32x32x16_bf16(ka0, qf[0], Z16, 0, 0, 0);
      o0  = __builtin_amdgcn_mfma_f32_32x32x16_bf16(pa[0], vf00, o0, 0, 0, 0);
      o1  = __builtin_amdgcn_mfma_f32_32x32x16_bf16(pa[0], vf01, o1, 0, 0, 0);
      prN = __builtin_amdgcn_mfma_f32_32x32x16_bf16(ka1, qf[1], prN, 0, 0, 0);
      o0  = __builtin_amdgcn_mfma_f32_32x32x16_bf16(pa[1], vf10, o0, 0, 0, 0);
      prN = __builtin_amdgcn_mfma_f32_32x32x16_bf16(ka2, qf[2], prN, 0, 0, 0);
      o1  = __builtin_amdgcn_mfma_f32_32x32x16_bf16(pa[1], vf11, o1, 0, 0, 0);
      prN = __builtin_amdgcn_mfma_f32_32x32x16_bf16(ka3, qf[3], prN, 0, 0, 0);
      pr = prN;
    } else {
      // final tile: PV only
      short8 vf00 = *(const short8*)&Vc[l31 * 64 + (((p * 4 + 0 + hi) ^ (l31 & 7)) * 8)];
      short8 vf01 = *(const short8*)&Vc[(32 + l31) * 64 + (((p * 4 + 0 + hi) ^ ((l31 & 7))) * 8)];
      short8 vf10 = *(const short8*)&Vc[l31 * 64 + (((p * 4 + 2 + hi) ^ (l31 & 7)) * 8)];
      short8 vf11 = *(const short8*)&Vc[(32 + l31) * 64 + (((p * 4 + 2 + hi) ^ ((l31 & 7))) * 8)];
      o0 = __builtin_amdgcn_mfma_f32_32x32x16_bf16(pa[0], vf00, o0, 0, 0, 0);
      o1 = __builtin_amdgcn_mfma_f32_32x32x16_bf16(pa[0], vf01, o1, 0, 0, 0);
      o0 = __builtin_amdgcn_mfma_f32_32x32x16_bf16(pa[1], vf10, o0, 0, 0, 0);
      o1 = __builtin_amdgcn_mfma_f32_32x32x16_bf16(pa[1], vf11, o1, 0, 0, 0);
    }
    __builtin_amdgcn_s_setprio(0);

    if (t < 31) SMPACK((t + 1) * 64)

    __builtin_amdgcn_s_barrier();   // buf[cur] fully dead (Ks read at t-1, Vs read now)
    if (t < 30) STAGE(cur, (t + 2) * 64)
  }
#undef STAGE
#undef SMPACK

  __syncthreads();   // all waves done with Ks/Vs before LDS reuse below

  // ---- additive parity merge (no-max softmax => O and l just sum) ----
  float* Ox = (float*)&Ks[0][0];       // [g][32 sr][64 col] f32 = 16 KB
  float* Ml = (float*)&Vs[0][0];       // [g][32] f32
  float lt = l_r + __shfl_xor(l_r, 32);    // own-parity row sum (both hi halves)
  if (p == 1) {
#pragma unroll
    for (int r = 0; r < 16; ++r) {
      int sr = (r & 3) + 8 * (r >> 2) + 4 * hi;
      Ox[g * 2048 + sr * 64 + l31]      = o0[r];
      Ox[g * 2048 + sr * 64 + 32 + l31] = o1[r];
    }
    if (hi == 0) Ml[g * 32 + l31] = lt;
  }
  __syncthreads();
  if (p == 0) {
    const int b = bh >> 4, h = bh & 15;
    float ltot = lt + Ml[g * 32 + l31];
    float linv = ltot > 0.f ? 1.0f / ltot : 0.f;
#pragma unroll
    for (int r = 0; r < 16; ++r) {
      int sr = (r & 3) + 8 * (r >> 2) + 4 * hi;
      float li = __shfl(linv, sr);
      size_t rowbase = (size_t)(b * Ss + s0 + sr) * Ee + h * 64;
      Ob[rowbase + l31]      = f2bf((o0[r] + Ox[g * 2048 + sr * 64 + l31]) * li);
      Ob[rowbase + 32 + l31] = f2bf((o1[r] + Ox[g * 2048 + sr * 64 + 32 + l31]) * li);
    }
  }
}

extern "C" void kernel_launch(void* const* d_in, const int* in_sizes, int n_in,
                              void* d_out, int out_size, void* d_ws, size_t ws_size,
                              hipStream_t stream) {
  const float* q   = (const float*)d_in[0];
  const float* k   = (const float*)d_in[1];
  const float* v   = (const float*)d_in[2];
  const int*  msk  = (const int*)d_in[3];
  const float* Wq  = (const float*)d_in[4];
  const float* bq  = (const float*)d_in[5];
  const float* Wk  = (const float*)d_in[6];
  const float* bk  = (const float*)d_in[7];
  const float* Wv  = (const float*)d_in[8];
  const float* bv  = (const float*)d_in[9];
  const float* Wo  = (const float*)d_in[10];
  const float* bo  = (const float*)d_in[11];
  float* out = (float*)d_out;

  char* ws = (char*)d_ws;
  unsigned short* Wqb = (unsigned short*)(ws + OFF_WQ);
  unsigned short* Wkb = (unsigned short*)(ws + OFF_WK);
  unsigned short* Wvb = (unsigned short*)(ws + OFF_WV);
  unsigned short* Wob = (unsigned short*)(ws + OFF_WO);
  unsigned short* Qh  = (unsigned short*)(ws + OFF_QH);
  unsigned short* Kh  = (unsigned short*)(ws + OFF_KH);
  unsigned short* Vh  = (unsigned short*)(ws + OFF_VH);
  unsigned short* Ob  = (unsigned short*)(ws + OFF_OB);
  int* flagZero       = (int*)(ws + OFF_FLAG);

  hipMemsetAsync(flagZero, 0, 4, stream);
  prep_kernel<<<2048, 256, 0, stream>>>(Wq, Wk, Wv, Wo, msk,
                                        Wqb, Wkb, Wvb, Wob, flagZero);
  gemm_qkv<<<dim3(8, 32, 3), 256, 0, stream>>>(q, k, v, Wqb, Wkb, Wvb,
                                               bq, bk, bv, Qh, Kh, Vh);
  attn_kernel<<<dim3(32, 32), 256, 0, stream>>>(Qh, Kh, Vh, msk, flagZero, Ob);
  gemm_out<<<dim3(8, 32), 512, 0, stream>>>(Ob, Wob, bo, out);
}